// Round 1
// baseline (1189.799 us; speedup 1.0000x reference)
//
#include <hip/hip_runtime.h>

#define HID 1024
#define HEADS 16
#define HD 64
#define TAB 129
#define BATCH 8
#define SEQ 512

// ---------------------------------------------------------------------------
// C[M,N] = A[M,K] @ W[N,K]^T + bias[N]   (both operands row-major, "NT" gemm)
// 128x128 tile, BK=16, 256 threads, 8x8 per thread, fp32.
// ---------------------------------------------------------------------------
__global__ __launch_bounds__(256) void gemm_nt_bias(const float* __restrict__ A,
                                                    const float* __restrict__ W,
                                                    const float* __restrict__ bias,
                                                    float* __restrict__ C,
                                                    int M, int N, int K) {
    __shared__ float As[16][132];
    __shared__ float Ws[16][132];
    const int tid = threadIdx.x;
    const int m0 = blockIdx.y * 128;
    const int n0 = blockIdx.x * 128;
    const int tx = tid & 15;   // n-dir
    const int ty = tid >> 4;   // m-dir
    const int lr = tid >> 2;       // 0..63 row within half-tile
    const int lk = (tid & 3) << 2; // 0,4,8,12

    float acc[8][8];
#pragma unroll
    for (int i = 0; i < 8; ++i)
#pragma unroll
        for (int j = 0; j < 8; ++j) acc[i][j] = 0.f;

    const float* Arow0 = A + (size_t)(m0 + lr) * K + lk;
    const float* Arow1 = A + (size_t)(m0 + lr + 64) * K + lk;
    const float* Wrow0 = W + (size_t)(n0 + lr) * K + lk;
    const float* Wrow1 = W + (size_t)(n0 + lr + 64) * K + lk;

    for (int k0 = 0; k0 < K; k0 += 16) {
        float4 a0 = *(const float4*)(Arow0 + k0);
        float4 a1 = *(const float4*)(Arow1 + k0);
        float4 w0 = *(const float4*)(Wrow0 + k0);
        float4 w1 = *(const float4*)(Wrow1 + k0);
        __syncthreads();   // previous iteration's readers done
        As[lk+0][lr]    = a0.x; As[lk+1][lr]    = a0.y; As[lk+2][lr]    = a0.z; As[lk+3][lr]    = a0.w;
        As[lk+0][lr+64] = a1.x; As[lk+1][lr+64] = a1.y; As[lk+2][lr+64] = a1.z; As[lk+3][lr+64] = a1.w;
        Ws[lk+0][lr]    = w0.x; Ws[lk+1][lr]    = w0.y; Ws[lk+2][lr]    = w0.z; Ws[lk+3][lr]    = w0.w;
        Ws[lk+0][lr+64] = w1.x; Ws[lk+1][lr+64] = w1.y; Ws[lk+2][lr+64] = w1.z; Ws[lk+3][lr+64] = w1.w;
        __syncthreads();
#pragma unroll
        for (int kk = 0; kk < 16; ++kk) {
            float4 av0 = *(const float4*)&As[kk][ty*8];
            float4 av1 = *(const float4*)&As[kk][ty*8+4];
            float4 wv0 = *(const float4*)&Ws[kk][tx*8];
            float4 wv1 = *(const float4*)&Ws[kk][tx*8+4];
            float am[8] = {av0.x, av0.y, av0.z, av0.w, av1.x, av1.y, av1.z, av1.w};
            float wn[8] = {wv0.x, wv0.y, wv0.z, wv0.w, wv1.x, wv1.y, wv1.z, wv1.w};
#pragma unroll
            for (int i = 0; i < 8; ++i)
#pragma unroll
                for (int j = 0; j < 8; ++j)
                    acc[i][j] = fmaf(am[i], wn[j], acc[i][j]);
        }
    }
#pragma unroll
    for (int i = 0; i < 8; ++i) {
        int m = m0 + ty*8 + i;
#pragma unroll
        for (int jj = 0; jj < 2; ++jj) {
            int n = n0 + tx*8 + jj*4;
            float4 bv = *(const float4*)&bias[n];
            float4 o;
            o.x = acc[i][jj*4+0] + bv.x;
            o.y = acc[i][jj*4+1] + bv.y;
            o.z = acc[i][jj*4+2] + bv.z;
            o.w = acc[i][jj*4+3] + bv.w;
            *(float4*)&C[(size_t)m * N + n] = o;
        }
    }
}

// ---------------------------------------------------------------------------
// qtab[b,h,q,t] = sum_d q4[b,q,h,d] * table_k[t,d]
// one block = (b, h, 64 q-rows)
// ---------------------------------------------------------------------------
__global__ __launch_bounds__(256) void qtab_kernel(const float* __restrict__ q4,
                                                   const float* __restrict__ table_k,
                                                   float* __restrict__ qtab) {
    __shared__ float qs[64][68];
    __shared__ float tk[TAB][68];
    const int tid = threadIdx.x;
    const int q0 = blockIdx.x * 64;
    const int h  = blockIdx.y;
    const int b  = blockIdx.z;
    {
        int f = tid;
#pragma unroll
        for (int j = 0; j < 4; ++j, f += 256) {
            int r  = f >> 4;
            int dd = (f & 15) << 2;
            *(float4*)&qs[r][dd] =
                *(const float4*)&q4[((size_t)(b*SEQ + q0 + r)) * HID + h*HD + dd];
        }
    }
    for (int f = tid; f < TAB*16; f += 256) {
        int t  = f >> 4;
        int dd = (f & 15) << 2;
        *(float4*)&tk[t][dd] = *(const float4*)&table_k[t*HD + dd];
    }
    __syncthreads();
    const int tq = tid >> 2;
    const int tg = tid & 3;
    float* outrow = qtab + ((size_t)(b*HEADS + h) * SEQ + q0 + tq) * TAB;
    for (int t = tg; t < TAB; t += 4) {
        float s = 0.f;
#pragma unroll
        for (int d = 0; d < HD; d += 4) {
            float4 qa = *(const float4*)&qs[tq][d];
            float4 ta = *(const float4*)&tk[t][d];
            s = fmaf(qa.x, ta.x, s); s = fmaf(qa.y, ta.y, s);
            s = fmaf(qa.z, ta.z, s); s = fmaf(qa.w, ta.w, s);
        }
        outrow[t] = s;
    }
}

// ---------------------------------------------------------------------------
// Fused attention: one block = (b, h, 16 q-rows), full L=512 keys.
// scores -> softmax -> w1 (attn@v) + 129-bin mass -> w2 (bins@table_v) -> x
// ---------------------------------------------------------------------------
__global__ __launch_bounds__(256) void attn_kernel(const float* __restrict__ q4,
                                                   const float* __restrict__ k4,
                                                   const float* __restrict__ v4,
                                                   const float* __restrict__ qtab,
                                                   const int* __restrict__ fmat,
                                                   const float* __restrict__ table_v,
                                                   float* __restrict__ x) {
    __shared__ float S[16][516];     // scores, then attention probs
    __shared__ float kt[64][68];     // k-tile, then v-tile
    __shared__ float qs[16][68];
    __shared__ float qtb[16][132];   // qtab rows, reused as bin accumulator

    const int tid = threadIdx.x;
    const int q0 = blockIdx.x * 16;
    const int h  = blockIdx.y;
    const int b  = blockIdx.z;

    // load q rows (16 x 64)
    {
        int r  = tid >> 4;
        int dd = (tid & 15) << 2;
        *(float4*)&qs[r][dd] =
            *(const float4*)&q4[((size_t)(b*SEQ + q0 + r)) * HID + h*HD + dd];
    }
    // load qtab rows (16 x 129)
    {
        const float* src = qtab + ((size_t)(b*HEADS + h) * SEQ + q0) * TAB;
        for (int i = tid; i < 16*TAB; i += 256) {
            int r = i / TAB;
            int t = i - r*TAB;
            qtb[r][t] = src[i];
        }
    }

    // ---- Phase A: scores S[q][k] = (q.k + qtab[q][fm]) / 8 ----
    const int aq  = tid & 15;   // q row
    const int akb = tid >> 4;   // k sub-column 0..15
    for (int k0 = 0; k0 < SEQ; k0 += 64) {
        __syncthreads();
        {
            int f = tid;
#pragma unroll
            for (int j = 0; j < 4; ++j, f += 256) {
                int r  = f >> 4;
                int dd = (f & 15) << 2;
                *(float4*)&kt[r][dd] =
                    *(const float4*)&k4[((size_t)(b*SEQ + k0 + r)) * HID + h*HD + dd];
            }
        }
        __syncthreads();
        float acc[4] = {0.f, 0.f, 0.f, 0.f};
#pragma unroll
        for (int d = 0; d < HD; d += 4) {
            float4 qa = *(const float4*)&qs[aq][d];
#pragma unroll
            for (int j = 0; j < 4; ++j) {
                float4 ka = *(const float4*)&kt[akb + j*16][d];
                acc[j] = fmaf(qa.x, ka.x, acc[j]);
                acc[j] = fmaf(qa.y, ka.y, acc[j]);
                acc[j] = fmaf(qa.z, ka.z, acc[j]);
                acc[j] = fmaf(qa.w, ka.w, acc[j]);
            }
        }
        const int* fmrow = fmat + ((size_t)(b*SEQ) + q0 + aq) * SEQ + k0;
#pragma unroll
        for (int j = 0; j < 4; ++j) {
            int k = akb + j*16;
            int t = fmrow[k];
            S[aq][k0 + k] = (acc[j] + qtb[aq][t]) * 0.125f;
        }
    }
    __syncthreads();

    // ---- Phase B: softmax over each row of 512 ----
    {
        const int wave = tid >> 6;
        const int lane = tid & 63;
        for (int r = wave; r < 16; r += 4) {
            float vals[8];
            float vmax = -1e30f;
#pragma unroll
            for (int j = 0; j < 8; ++j) {
                vals[j] = S[r][lane + j*64];
                vmax = fmaxf(vmax, vals[j]);
            }
#pragma unroll
            for (int off = 32; off >= 1; off >>= 1)
                vmax = fmaxf(vmax, __shfl_xor(vmax, off));
            float vsum = 0.f;
#pragma unroll
            for (int j = 0; j < 8; ++j) {
                vals[j] = __expf(vals[j] - vmax);
                vsum += vals[j];
            }
#pragma unroll
            for (int off = 32; off >= 1; off >>= 1)
                vsum += __shfl_xor(vsum, off);
            float inv = 1.f / vsum;
#pragma unroll
            for (int j = 0; j < 8; ++j)
                S[r][lane + j*64] = vals[j] * inv;
        }
    }
    __syncthreads();

    // ---- bins: sbin[q][t] = sum_{k: fm[q][k]==t} attn[q][k]  (reuse qtb) ----
    for (int i = tid; i < 16*132; i += 256) (&qtb[0][0])[i] = 0.f;
    __syncthreads();
    {
        const int bq = tid & 15;
        const int ks = tid >> 4;
        const int* fmrow = fmat + ((size_t)(b*SEQ) + q0 + bq) * SEQ;
        for (int k = ks; k < SEQ; k += 16)
            atomicAdd(&qtb[bq][fmrow[k]], S[bq][k]);
    }

    // ---- Phase C: w1[q][d] = sum_k attn[q][k] * v[k][d] ----
    const int cq = tid >> 4;
    const int d0 = (tid & 15) << 2;
    float w1a0 = 0.f, w1a1 = 0.f, w1a2 = 0.f, w1a3 = 0.f;
    for (int k0 = 0; k0 < SEQ; k0 += 64) {
        __syncthreads();   // also orders the bin atomics before Phase D
        {
            int f = tid;
#pragma unroll
            for (int j = 0; j < 4; ++j, f += 256) {
                int r  = f >> 4;
                int dd = (f & 15) << 2;
                *(float4*)&kt[r][dd] =
                    *(const float4*)&v4[((size_t)(b*SEQ + k0 + r)) * HID + h*HD + dd];
            }
        }
        __syncthreads();
#pragma unroll 4
        for (int kk = 0; kk < 64; kk += 4) {
            float4 s4 = *(const float4*)&S[cq][k0 + kk];
            float4 v0 = *(const float4*)&kt[kk+0][d0];
            float4 v1 = *(const float4*)&kt[kk+1][d0];
            float4 v2 = *(const float4*)&kt[kk+2][d0];
            float4 v3 = *(const float4*)&kt[kk+3][d0];
            w1a0 = fmaf(s4.x, v0.x, w1a0); w1a1 = fmaf(s4.x, v0.y, w1a1);
            w1a2 = fmaf(s4.x, v0.z, w1a2); w1a3 = fmaf(s4.x, v0.w, w1a3);
            w1a0 = fmaf(s4.y, v1.x, w1a0); w1a1 = fmaf(s4.y, v1.y, w1a1);
            w1a2 = fmaf(s4.y, v1.z, w1a2); w1a3 = fmaf(s4.y, v1.w, w1a3);
            w1a0 = fmaf(s4.z, v2.x, w1a0); w1a1 = fmaf(s4.z, v2.y, w1a1);
            w1a2 = fmaf(s4.z, v2.z, w1a2); w1a3 = fmaf(s4.z, v2.w, w1a3);
            w1a0 = fmaf(s4.w, v3.x, w1a0); w1a1 = fmaf(s4.w, v3.y, w1a1);
            w1a2 = fmaf(s4.w, v3.z, w1a2); w1a3 = fmaf(s4.w, v3.w, w1a3);
        }
    }

    // ---- Phase D: w2[q][d] = sum_t sbin[q][t] * table_v[t][d]; write x ----
    {
        float w2a0 = 0.f, w2a1 = 0.f, w2a2 = 0.f, w2a3 = 0.f;
        for (int t = 0; t < TAB; ++t) {
            float sv = qtb[cq][t];
            float4 tv = *(const float4*)&table_v[t*HD + d0];
            w2a0 = fmaf(sv, tv.x, w2a0); w2a1 = fmaf(sv, tv.y, w2a1);
            w2a2 = fmaf(sv, tv.z, w2a2); w2a3 = fmaf(sv, tv.w, w2a3);
        }
        float4 o;
        o.x = w1a0 + w2a0; o.y = w1a1 + w2a1;
        o.z = w1a2 + w2a2; o.w = w1a3 + w2a3;
        *(float4*)&x[((size_t)(b*SEQ) + q0 + cq) * HID + h*HD + d0] = o;
    }
}

// ---------------------------------------------------------------------------
extern "C" void kernel_launch(void* const* d_in, const int* in_sizes, int n_in,
                              void* d_out, int out_size, void* d_ws, size_t ws_size,
                              hipStream_t stream) {
    const float* query = (const float*)d_in[0];
    const float* key   = (const float*)d_in[1];
    const float* value = (const float*)d_in[2];
    const int*   fmat  = (const int*)d_in[3];
    const float* Wq = (const float*)d_in[4];
    const float* bq = (const float*)d_in[5];
    const float* Wk = (const float*)d_in[6];
    const float* bk = (const float*)d_in[7];
    const float* Wv = (const float*)d_in[8];
    const float* bv = (const float*)d_in[9];
    const float* Wo = (const float*)d_in[10];
    const float* bo = (const float*)d_in[11];
    const float* table_k = (const float*)d_in[12];
    const float* table_v = (const float*)d_in[13];

    const size_t nBLD = (size_t)BATCH * SEQ * HID;        // 4,194,304
    float* ws = (float*)d_ws;
    float* qb = ws;
    float* kb = qb + nBLD;
    float* vb = kb + nBLD;
    float* qt = vb + nBLD;                                // B*H*L*TAB
    float* xb = qt + (size_t)BATCH * HEADS * SEQ * TAB;

    const int M = BATCH * SEQ;  // 4096
    dim3 ggrid(HID / 128, M / 128);

    gemm_nt_bias<<<ggrid, 256, 0, stream>>>(query, Wq, bq, qb, M, HID, HID);
    gemm_nt_bias<<<ggrid, 256, 0, stream>>>(key,   Wk, bk, kb, M, HID, HID);
    gemm_nt_bias<<<ggrid, 256, 0, stream>>>(value, Wv, bv, vb, M, HID, HID);

    qtab_kernel<<<dim3(SEQ/64, HEADS, BATCH), 256, 0, stream>>>(qb, table_k, qt);

    attn_kernel<<<dim3(SEQ/16, HEADS, BATCH), 256, 0, stream>>>(
        qb, kb, vb, qt, fmat, table_v, xb);

    gemm_nt_bias<<<ggrid, 256, 0, stream>>>(xb, Wo, bo, (float*)d_out, M, HID, HID);
}